// Round 8
// baseline (31.207 us; speedup 1.0000x reference)
//
#include <hip/hip_runtime.h>

typedef unsigned short ushort_t;
typedef unsigned int uint_t;
typedef __bf16 bf16x8 __attribute__((ext_vector_type(8)));
typedef float f32x4 __attribute__((ext_vector_type(4)));

#define H 256
#define RPB 16      // batch rows per block
#define NBLK 256    // 4096 / RPB

// output layout (f32): [nb 4096][bdot 4096][y 4096*256][yy 4096*64]
#define NB_OFF 0
#define BDOT_OFF 4096
#define Y_OFF 8192
#define YY_OFF (8192 + 4096 * 256)

__device__ __forceinline__ ushort_t f2bf(float x) {
    union { float f; uint_t u; } c; c.f = x;
    uint_t r = (c.u + 0x7FFFu + ((c.u >> 16) & 1u)) >> 16;  // RNE
    return (ushort_t)r;
}
__device__ __forceinline__ float bf2f(ushort_t v) {
    union { uint_t u; float f; } c; c.u = ((uint_t)v) << 16;
    return c.f;
}

// ws layout (ushort/bf16 units)
#define O_W1b  0        // [256][64]   orig (B for z)
#define O_W1T  16384    // [64][256]   W1T[i][g] = w1[g][i]
#define O_W2ab 32768    // [256][256]  orig
#define O_W2bb 98304
#define O_W3ab 163840
#define O_W2aT 229376   // [g][h] = w2a[h][g]
#define O_W2bT 294912
#define O_W3aT 360448   // [g][o] = wout[o]*w3a[o][g]   (wout folded)
#define O_W3sb 425984   // [256][64] orig
#define O_W3sT 442368   // [i][o] = wout[o]*w3s[o][i]   (wout folded)

__global__ __launch_bounds__(256) void prep_weights(
    const float* __restrict__ w1, const float* __restrict__ w2a,
    const float* __restrict__ w2b, const float* __restrict__ w3a,
    const float* __restrict__ w3s, const float* __restrict__ wout,
    ushort_t* __restrict__ ws) {
    __shared__ float tile[32][65];
    int b = blockIdx.x;
    const float* src; int Oo, Ot, C, t; bool scl;
    if (b < 32)       { src = w2a; Oo = O_W2ab; Ot = O_W2aT; C = 256; t = b;       scl = false; }
    else if (b < 64)  { src = w2b; Oo = O_W2bb; Ot = O_W2bT; C = 256; t = b - 32;  scl = false; }
    else if (b < 96)  { src = w3a; Oo = O_W3ab; Ot = O_W3aT; C = 256; t = b - 64;  scl = true;  }
    else if (b < 104) { src = w1;  Oo = O_W1b;  Ot = O_W1T;  C = 64;  t = b - 96;  scl = false; }
    else              { src = w3s; Oo = O_W3sb; Ot = O_W3sT; C = 64;  t = b - 104; scl = true;  }
    int tr, tc;
    if (C == 256) { tr = t >> 2; tc = t & 3; } else { tr = t; tc = 0; }
    int r0 = tr * 32, c0 = tc * 64;
    const int tid = threadIdx.x;

    union pack8 { ushort_t u[8]; uint4 q; };
    {
        int r = tid >> 3, c8 = (tid & 7) << 3;
        const float* s = src + (r0 + r) * C + c0 + c8;
        pack8 p;
#pragma unroll
        for (int j = 0; j < 8; j++) { float v = s[j]; tile[r][c8 + j] = v; p.u[j] = f2bf(v); }
        *(uint4*)(ws + Oo + (r0 + r) * C + c0 + c8) = p.q;
    }
    __syncthreads();
    {
        int cc = tid >> 2, r8 = (tid & 3) << 3;
        pack8 p;
#pragma unroll
        for (int j = 0; j < 8; j++) {
            float v = tile[r8 + j][cc];
            if (scl) v *= wout[r0 + r8 + j];
            p.u[j] = f2bf(v);
        }
        *(uint4*)(ws + Ot + (c0 + cc) * 256 + r0 + r8) = p.q;
    }
}

// dynamic smem layout (ushort units)
#define RS 5            // ring slots per wave (512 ushorts = 1KB each)
#define RA 4            // units in flight per wave
#define U_RING 0        // 16 waves * 5 * 512 = 40960
#define U_Z    40960    // z -> c2 (in place)
#define U_Y    45056    // y1; later z1_3 (alias)
#define U_Z12  49152    // z1_2 -> t*z1_2
#define U_Z22  53248    // z2_2 -> t*z2_2
#define U_Z23  57344    // z2_3; later FJ[0..1] f32 (alias)
#define U_U    61440    // y2;   later FJ[2..3] f32 (alias)
#define U_XD   65536    // f32 [1024]
#define U_NB   69632    // f32 [16]
#define SMEM_USHORTS 69664
#define SMEM_BYTES (SMEM_USHORTS * 2)

__device__ __forceinline__ void gload16(const ushort_t* g, ushort_t* l) {
    __builtin_amdgcn_global_load_lds(
        (const __attribute__((address_space(1))) void*)g,
        (__attribute__((address_space(3))) void*)l, 16, 0, 0);
}

template <int N> __device__ __forceinline__ void vwait() {
    if constexpr (N == 3) asm volatile("s_waitcnt vmcnt(3)" ::: "memory");
    else if constexpr (N == 2) asm volatile("s_waitcnt vmcnt(2)" ::: "memory");
    else if constexpr (N == 1) asm volatile("s_waitcnt vmcnt(1)" ::: "memory");
    else asm volatile("s_waitcnt vmcnt(0)" ::: "memory");
}

#define PHASE_BARRIER() do { \
    asm volatile("s_waitcnt lgkmcnt(0)" ::: "memory"); \
    __builtin_amdgcn_sched_barrier(0); \
    __builtin_amdgcn_s_barrier(); \
    __builtin_amdgcn_sched_barrier(0); \
} while (0)

__device__ __forceinline__ int posw(int r, int c) { return r * H + (c ^ ((r & 7) << 3)); }

// One sub-phase (16 units = 2 matrices x 8 k-chunks) of the continuous ring
// pipeline. Units stream in global order u = P*16 + k; unit u's slot is u%RS;
// restage of unit u+RA goes to the slot read at iteration u-1 (RS>RA), guarded
// by lgkmcnt(2). vmcnt counts ONLY ring gloads mid-stream (no global stores
// issued between prologue and drain). gn0/gn1 = next sub-phase's matrices.
template <int P, bool SUM>
__device__ __forceinline__ void ring_phase(
    const ushort_t* __restrict__ gm0, const ushort_t* __restrict__ gm1,
    const ushort_t* __restrict__ gn0, const ushort_t* __restrict__ gn1,
    const ushort_t* aP0, const ushort_t* aP1,
    ushort_t* rw, int srcoff, int boff, int kq, int sw,
    f32x4& acc0, f32x4& acc1) {
#pragma unroll
    for (int k = 0; k < 16; ++k) {
        const int u = P * 16 + k;
        if (P == 2) {
            if (k < 13) vwait<3>();
            else if (k == 13) vwait<2>();
            else if (k == 14) vwait<1>();
            else vwait<0>();
        } else {
            vwait<3>();
        }
        __builtin_amdgcn_sched_barrier(0);
        bf16x8 b = *(const bf16x8*)(rw + (u % RS) * 512 + boff);
        const ushort_t* ap = (k & 1) ? aP1 : aP0;
        bf16x8 a = *(const bf16x8*)(ap + ((((k >> 1) << 5) + kq) ^ sw));
        if (u + RA < 48) {
            asm volatile("s_waitcnt lgkmcnt(2)" ::: "memory");
            __builtin_amdgcn_sched_barrier(0);
            const int k4 = k + RA;
            const ushort_t* g = (k4 < 16) ? ((k4 & 1) ? gm1 : gm0)
                                          : ((k4 & 1) ? gn1 : gn0);
            const int cc = (k4 & 15) >> 1;
            gload16(g + srcoff + (cc << 5), rw + ((u + RA) % RS) * 512);
        }
        if (SUM)
            acc0 = __builtin_amdgcn_mfma_f32_16x16x32_bf16(a, b, acc0, 0, 0, 0);
        else if ((k & 1) == 0)
            acc0 = __builtin_amdgcn_mfma_f32_16x16x32_bf16(a, b, acc0, 0, 0, 0);
        else
            acc1 = __builtin_amdgcn_mfma_f32_16x16x32_bf16(a, b, acc1, 0, 0, 0);
    }
}

// register-path tile GEMM (small matrices), batched loads + sched fence
template <int NF, int STRA, int STRB>
__device__ __forceinline__ void gemm_one(const ushort_t* sA, const ushort_t* __restrict__ B0,
                                         int lane, int k0, f32x4& acc0) {
    const int row = lane & 15;
    const int kq = (lane >> 4) << 3;
    const int sw = (row & 7) << 3;
    bf16x8 b0[NF], a[NF];
    const ushort_t* bp0 = B0 + row * STRB + k0 + kq;
    const ushort_t* ap = sA + row * STRA;
#pragma unroll
    for (int i = 0; i < NF; i++) b0[i] = *(const bf16x8*)(bp0 + i * 32);
#pragma unroll
    for (int i = 0; i < NF; i++) a[i] = *(const bf16x8*)(ap + ((k0 + i * 32 + kq) ^ sw));
    __builtin_amdgcn_sched_barrier(0);
#pragma unroll
    for (int i = 0; i < NF; i++)
        acc0 = __builtin_amdgcn_mfma_f32_16x16x32_bf16(a[i], b0[i], acc0, 0, 0, 0);
}

__global__ __launch_bounds__(1024) void net_main(
    const float* __restrict__ x, const float* __restrict__ xd,
    const float* __restrict__ b1, const float* __restrict__ b2a,
    const float* __restrict__ b2b, const float* __restrict__ b3a,
    const float* __restrict__ b3s, const float* __restrict__ wout,
    const float* __restrict__ scalar, const ushort_t* __restrict__ ws,
    float* __restrict__ out) {
    extern __shared__ __align__(16) ushort_t smem[];
    ushort_t* sZ   = smem + U_Z;
    ushort_t* sY   = smem + U_Y;    // y1, then z1_3
    ushort_t* sZ12 = smem + U_Z12;
    ushort_t* sZ22 = smem + U_Z22;
    ushort_t* sZ23 = smem + U_Z23;  // z2_3, then FJ[0..1]
    ushort_t* sU   = smem + U_U;    // y2, then FJ[2..3]
    float* sXd = (float*)(smem + U_XD);
    float* sNB = (float*)(smem + U_NB);

    const int tid = threadIdx.x;
    const int wid = tid >> 6;     // 0..15
    const int lane = tid & 63;
    const int row16 = lane & 15;  // MFMA D column-within-tile
    const int rq = lane >> 4;     // MFMA D row = rq*4 + i
    const int R0 = blockIdx.x * RPB;
    const int n0 = wid * 16;      // this wave's 16-col tile
    const int kq = rq << 3;
    const int sw = (row16 & 7) << 3;

    ushort_t* rw = smem + U_RING + wid * (RS * 512);
    const int srcoff = ((wid << 4) + (lane >> 2)) * 256 + (lane & 3) * 8;
    const int boff = row16 * 32 + rq * 8;

    const ushort_t* gW2ab = ws + O_W2ab;
    const ushort_t* gW2bb = ws + O_W2bb;
    const ushort_t* gW3ab = ws + O_W3ab;
    const ushort_t* gW3aT = ws + O_W3aT;
    const ushort_t* gW2bT = ws + O_W2bT;
    const ushort_t* gW2aT = ws + O_W2aT;

    // ---- P1: issue all early loads, ring prologue; z/z2_3 MFMAs; epilogue.
    f32x4 y3keep;
    {
        const ushort_t* w1p = ws + O_W1b + (n0 + row16) * 64 + kq;
        const ushort_t* w3p = ws + O_W3sb + (n0 + row16) * 64 + kq;
        bf16x8 pb0 = *(const bf16x8*)(w1p);
        bf16x8 pb1 = *(const bf16x8*)(w1p + 32);
        bf16x8 pb2 = *(const bf16x8*)(w3p);
        bf16x8 pb3 = *(const bf16x8*)(w3p + 32);
        const float* xg = x + (R0 + row16) * 64;
        float4 x0 = *(const float4*)(xg + kq);
        float4 x1 = *(const float4*)(xg + kq + 4);
        float4 x2 = *(const float4*)(xg + 32 + kq);
        float4 x3 = *(const float4*)(xg + 32 + kq + 4);
        int xr = tid >> 6, xc = tid & 63;
        float xdv = xd[(R0 + xr) * 64 + xc];
        float sc = scalar[0];
        // ring prologue: units 0..3 (W2ab c0, W2bb c0, W2ab c1, W2bb c1)
        gload16(gW2ab + srcoff, rw);
        gload16(gW2bb + srcoff, rw + 512);
        gload16(gW2ab + srcoff + 32, rw + 1024);
        gload16(gW2bb + srcoff + 32, rw + 1536);
        __builtin_amdgcn_sched_barrier(0);
        // overlapped scalar work
        out[YY_OFF + (R0 + xr) * 64 + xc] = sc;
        sXd[tid] = xdv;
        if (tid < RPB) sNB[tid] = 0.f;
        union { ushort_t u[8]; bf16x8 v; } A0, A1;
#pragma unroll
        for (int j = 0; j < 4; j++) {
            A0.u[j]     = f2bf(((const float*)&x0)[j]);
            A0.u[4 + j] = f2bf(((const float*)&x1)[j]);
            A1.u[j]     = f2bf(((const float*)&x2)[j]);
            A1.u[4 + j] = f2bf(((const float*)&x3)[j]);
        }
        f32x4 z = {0.f,0.f,0.f,0.f}, q = {0.f,0.f,0.f,0.f};
        z = __builtin_amdgcn_mfma_f32_16x16x32_bf16(A0.v, pb0, z, 0, 0, 0);
        z = __builtin_amdgcn_mfma_f32_16x16x32_bf16(A1.v, pb1, z, 0, 0, 0);
        q = __builtin_amdgcn_mfma_f32_16x16x32_bf16(A0.v, pb2, q, 0, 0, 0);
        q = __builtin_amdgcn_mfma_f32_16x16x32_bf16(A1.v, pb3, q, 0, 0, 0);
        int c = n0 + row16;
        float bz = b1[c], bs = b3s[c];
#pragma unroll
        for (int i = 0; i < 4; i++) {
            int r = rq * 4 + i;
            int p = posw(r, c);
            float za = z[i] + bz;
            sZ[p] = f2bf(za);
            sY[p] = f2bf(za * za);
            sZ23[p] = f2bf(q[i] + bs);
        }
    }
    PHASE_BARRIER();

    const ushort_t* aRow = (const ushort_t*)0;  // silence unused warn pattern
    (void)aRow;
    const int arow = row16 * H;

    // ---- P2 (ring 0..15): z1_2 = y1@W2a.T, z2_2 = y1@W2b.T; y2 -> sU
    {
        f32x4 aA = {0.f,0.f,0.f,0.f}, aB = {0.f,0.f,0.f,0.f};
        ring_phase<0, false>(gW2ab, gW2bb, gW3ab, gW3aT, sY + arow, sY + arow,
                             rw, srcoff, boff, kq, sw, aA, aB);
        int c = n0 + row16;
        float ba = b2a[c], bb = b2b[c];
#pragma unroll
        for (int i = 0; i < 4; i++) {
            int r = rq * 4 + i;
            int p = posw(r, c);
            float z12 = aA[i] + ba, z22 = aB[i] + bb;
            sZ12[p] = f2bf(z12);
            sZ22[p] = f2bf(z22);
            sU[p] = f2bf(z12 * z22);
        }
    }
    PHASE_BARRIER();

    // ---- P4 (ring 16..31): z1_3 = y2@W3a.T + b3a; t = z2_3@(wout.w3a)T
    {
        f32x4 zz = {0.f,0.f,0.f,0.f}, tt = {0.f,0.f,0.f,0.f};
        ring_phase<1, false>(gW3ab, gW3aT, gW2bT, gW2aT, sU + arow, sZ23 + arow,
                             rw, srcoff, boff, kq, sw, zz, tt);
        int c = n0 + row16;
        float ba = b3a[c], wo = wout[c];
#pragma unroll
        for (int i = 0; i < 4; i++) {
            int r = rq * 4 + i;
            int p = posw(r, c);
            float z13 = zz[i] + ba;
            float z23 = bf2f(sZ23[p]);
            float y3 = z13 * z23;
            y3keep[i] = y3;                    // defer global store past the ring
            sY[p] = f2bf(z13);                 // sY now holds z1_3
            float t = tt[i];
            sZ12[p] = f2bf(t * bf2f(sZ12[p]));
            sZ22[p] = f2bf(t * bf2f(sZ22[p]));
            float v = wo * y3;
            v += __shfl_xor(v, 1);
            v += __shfl_xor(v, 2);
            v += __shfl_xor(v, 4);
            v += __shfl_xor(v, 8);
            if (row16 == 0) atomicAdd(&sNB[r], v);
        }
    }
    PHASE_BARRIER();

    // ---- P6 (ring 32..47): p = tz1@W2bT + tz2@W2aT ; c2 = 2*p*z
    {
        f32x4 pp = {0.f,0.f,0.f,0.f}, dummy = {0.f,0.f,0.f,0.f};
        ring_phase<2, true>(gW2bT, gW2aT, gW2bT, gW2aT, sZ12 + arow, sZ22 + arow,
                            rw, srcoff, boff, kq, sw, pp, dummy);
        int c = n0 + row16;
#pragma unroll
        for (int i = 0; i < 4; i++) {
            int r = rq * 4 + i;
            int p = posw(r, c);
            sZ[p] = f2bf(2.f * pp[i] * bf2f(sZ[p]));
        }
    }
    PHASE_BARRIER();

    // ---- P7: y3 stores; fj1 = z1_3@(wout.w3s)T, fj2 = c2@W1T
    {
        int c = n0 + row16;
#pragma unroll
        for (int i = 0; i < 4; i++)
            out[Y_OFF + (R0 + rq * 4 + i) * H + c] = y3keep[i];
        int mat = wid >> 3, kh = (wid >> 2) & 1, nt = wid & 3;
        const ushort_t* A = mat ? sZ : sY;
        const ushort_t* B = ws + (mat ? O_W1T : O_W3sT) + nt * 16 * H;
        f32x4 acc = {0.f,0.f,0.f,0.f};
        gemm_one<4, H, H>(A, B, lane, kh * 128, acc);
        float* F01 = (float*)sZ23;
        float* F23 = (float*)sU;
        float* dst = mat ? (F23 + kh * 1024) : (F01 + kh * 1024);
        int cc = nt * 16 + row16;
#pragma unroll
        for (int i = 0; i < 4; i++) dst[(rq * 4 + i) * 64 + cc] = acc[i];
    }
    PHASE_BARRIER();

    // ---- P8: bdot + nb writes
    {
        float* F0 = (float*)sZ23;
        float* F1 = F0 + 1024;
        float* F2 = (float*)sU;
        float* F3 = F2 + 1024;
        int r = tid >> 6, j = tid & 63;
        int e = r * 64 + j;
        float s = (F0[e] + F1[e] + F2[e] + F3[e]) * sXd[e];
        s += __shfl_xor(s, 1);
        s += __shfl_xor(s, 2);
        s += __shfl_xor(s, 4);
        s += __shfl_xor(s, 8);
        s += __shfl_xor(s, 16);
        s += __shfl_xor(s, 32);
        if (j == 0) out[BDOT_OFF + R0 + r] = s;
        if (tid < RPB) out[NB_OFF + R0 + tid] = sNB[tid];
    }
}

extern "C" void kernel_launch(void* const* d_in, const int* in_sizes, int n_in,
                              void* d_out, int out_size, void* d_ws, size_t ws_size,
                              hipStream_t stream) {
    (void)in_sizes; (void)n_in; (void)out_size; (void)ws_size;
    const float* x = (const float*)d_in[0];
    const float* xd = (const float*)d_in[1];
    const float* w1 = (const float*)d_in[2];
    const float* b1 = (const float*)d_in[3];
    const float* w2a = (const float*)d_in[4];
    const float* b2a = (const float*)d_in[5];
    const float* w2b = (const float*)d_in[6];
    const float* b2b = (const float*)d_in[7];
    const float* w3a = (const float*)d_in[8];
    const float* b3a = (const float*)d_in[9];
    const float* w3s = (const float*)d_in[10];
    const float* b3s = (const float*)d_in[11];
    const float* wout = (const float*)d_in[12];
    const float* scalar = (const float*)d_in[13];
    ushort_t* ws = (ushort_t*)d_ws;
    float* out = (float*)d_out;

    static bool attr_set = false;
    if (!attr_set) {
        hipFuncSetAttribute((const void*)net_main,
                            hipFuncAttributeMaxDynamicSharedMemorySize, SMEM_BYTES);
        attr_set = true;
    }

    prep_weights<<<112, 256, 0, stream>>>(w1, w2a, w2b, w3a, w3s, wout, ws);
    net_main<<<NBLK, 1024, SMEM_BYTES, stream>>>(x, xd, b1, b2a, b2b, b3a, b3s, wout, scalar, ws, out);
}